// Round 13
// baseline (343.024 us; speedup 1.0000x reference)
//
#include <hip/hip_runtime.h>
#include <hip/hip_fp16.h>
#include <math.h>

typedef unsigned int uint;
typedef unsigned short ushort;

#define B_ 256
#define T_ 512
#define F_ 378
#define C_ 128
#define H_ 64
#define KPAD 1152   // 3 * 384

using f32x4 = __attribute__((ext_vector_type(4))) float;
using bf16x8 = __attribute__((ext_vector_type(8))) short;
using f16x8 = __attribute__((ext_vector_type(8))) _Float16;

__device__ __forceinline__ ushort f2bf(float f) {
  union { float f; uint u; } c; c.f = f;
  uint r = (c.u + 0x7fffu + ((c.u >> 16) & 1u)) >> 16;
  return (ushort)r;
}
__device__ __forceinline__ uint packbf2(float a, float b) {
  return (uint)f2bf(a) | (((uint)f2bf(b)) << 16);
}
__device__ __forceinline__ ushort f2h(float f) {
  __half h = __float2half(f);
  return *(ushort*)&h;
}
__device__ __forceinline__ float h2f(ushort u) {
  __half h;
  *(ushort*)&h = u;
  return __half2float(h);
}
#define SC_SIG -1.442695041f
#define SC_TANH 2.885390082f

// ---------------- pack conv w -> wbT[c][kk], kk = k*384+f, bf16 ------------
__global__ __launch_bounds__(256) void pack_w_kernel(
    const float* __restrict__ w, ushort* __restrict__ wbT) {
  int i = blockIdx.x * 256 + threadIdx.x;
  if (i >= C_ * KPAD) return;
  int c = i / KPAD, kk = i - c * KPAD;
  int k = kk / 384, f = kk - k * 384;
  float v = (f < F_) ? w[c * (F_ * 3) + f * 3 + k] : 0.f;
  wbT[i] = f2bf(v);
}

// ---- pack w_ih -> wiP2[dir][r][128] bf16, PRE-SCALED, whhP row order ------
// r = 64w + 16n + 4q + e -> gate e of unit 16w + 4q + n (A-frag rows for the
// in-scan xg MFMA). Scale: i,f,o by -1.4427 (sigm), g by +2.8854 (tanh).
__global__ __launch_bounds__(256) void pack_wiP2_kernel(
    const float* __restrict__ wf, const float* __restrict__ wb,
    ushort* __restrict__ wiP2) {
  int i = blockIdx.x * 256 + threadIdx.x;  // 2*256*128 = 65536
  int dir = i >> 15, rem = i & 32767;
  int rr = rem >> 7, k = rem & 127;
  int e = rr & 3, qq = (rr >> 2) & 3, n = (rr >> 4) & 3, w = rr >> 6;
  int u = 16 * w + 4 * qq + n;
  const float* src = dir ? wb : wf;
  float scale = (e == 2) ? SC_TANH : SC_SIG;
  wiP2[i] = f2bf(src[(e * 64 + u) * 128 + k] * scale);
}

// ---- pack w_hh -> whhP[dir][r][64] FP16, PRE-SCALED (4-wave mapping) ------
__global__ __launch_bounds__(256) void pack_whhP_kernel(
    const float* __restrict__ wf, const float* __restrict__ wb,
    ushort* __restrict__ whhP) {
  int i = blockIdx.x * 256 + threadIdx.x;  // 2*256*64 = 32768
  if (i >= 32768) return;
  int dir = i >> 14, rem = i & 16383;
  int r = rem >> 6, k = rem & 63;
  int e = r & 3, q = (r >> 2) & 3, n = (r >> 4) & 3, w = r >> 6;
  int u = 16 * w + 4 * q + n;
  const float* src = dir ? wb : wf;
  float scale = (e == 2) ? SC_TANH : SC_SIG;
  whhP[i] = f2h(src[(e * 64 + u) * 64 + k] * scale);
}

// ---- pack bias -> biasP2[dir][r] fp32, same row order as whhP/wiP2 --------
__global__ __launch_bounds__(256) void pack_biasP2_kernel(
    const float* __restrict__ bf, const float* __restrict__ bb,
    float* __restrict__ biasP2) {
  int i = blockIdx.x * 256 + threadIdx.x;  // 512
  if (i >= 512) return;
  int dir = i >> 8, rr = i & 255;
  int e = rr & 3, qq = (rr >> 2) & 3, n = (rr >> 4) & 3, w = rr >> 6;
  int u = 16 * w + 4 * qq + n;
  const float* src = dir ? bb : bf;
  float scale = (e == 2) ? SC_TANH : SC_SIG;
  biasP2[i] = src[e * 64 + u] * scale;
}

// ---------------- Conv1d as implicit GEMM, bf16 MFMA (unchanged) -----------
__global__ __launch_bounds__(256, 2) void conv_gemm_kernel(
    const float* __restrict__ x, const ushort* __restrict__ wbT,
    const float* __restrict__ bias, ushort* __restrict__ y) {
  __shared__ __align__(16) char xsb[130 * 128];
  __shared__ __align__(16) char bsb[128 * 384];
  const int tid = threadIdx.x;
  const int lane = tid & 63;
  const int wr = (tid >> 7) & 1;
  const int wc = (tid >> 6) & 1;
  const int b = blockIdx.x >> 2;
  const int t0 = (blockIdx.x & 3) << 7;

  f32x4 acc[4][4];
#pragma unroll
  for (int m = 0; m < 4; ++m)
#pragma unroll
    for (int n = 0; n < 4; ++n) acc[m][n] = (f32x4)(0.f);

  for (int fs = 0; fs < 6; ++fs) {
    __syncthreads();
    {
      auto stage_a = [&](int r, int h) {
        const int t = t0 - 1 + r;
        const bool ok = (t >= 0) && (t < T_);
        const float* srow = x + ((long)b * T_ + (ok ? t : 0)) * F_;
        const int fb = fs * 64 + h * 32;
        char* dst = xsb + r * 128;
        const int sw = (r & 7) << 4;
        uint pk[16];
        if (ok && fb + 31 < F_) {
#pragma unroll
          for (int j = 0; j < 16; ++j) {
            float2 v = *(const float2*)(srow + fb + 2 * j);
            pk[j] = packbf2(v.x, v.y);
          }
        } else {
#pragma unroll
          for (int j = 0; j < 16; ++j) {
            const int f = fb + 2 * j;
            float a = (ok && f < F_) ? srow[f] : 0.f;
            float c2 = (ok && f + 1 < F_) ? srow[f + 1] : 0.f;
            pk[j] = packbf2(a, c2);
          }
        }
#pragma unroll
        for (int j = 0; j < 4; ++j) {
          uint4 p = {pk[4 * j], pk[4 * j + 1], pk[4 * j + 2], pk[4 * j + 3]};
          *(uint4*)(dst + ((h * 64 + j * 16) ^ sw)) = p;
        }
      };
      stage_a(tid >> 1, tid & 1);
      if (tid < 4) stage_a(128 + (tid >> 1), tid & 1);
    }
    {
      const int c = tid >> 1, h = tid & 1;
      const ushort* src = wbT + c * KPAD + fs * 64 + h * 32;
      char* drow = bsb + c * 384;
      const int sw = (c & 7) << 4;
#pragma unroll
      for (int k = 0; k < 3; ++k)
#pragma unroll
        for (int j = 0; j < 4; ++j) {
          uint4 v = *(const uint4*)(src + k * 384 + j * 8);
          *(uint4*)(drow + k * 128 + ((h * 64 + j * 16) ^ sw)) = v;
        }
    }
    __syncthreads();

#pragma unroll
    for (int k = 0; k < 3; ++k) {
#pragma unroll
      for (int s = 0; s < 2; ++s) {
        bf16x8 af[4], bfx[4];
        const int ksub = s * 64 + ((lane >> 4) << 4);
#pragma unroll
        for (int m = 0; m < 4; ++m) {
          const int rr = wr * 64 + m * 16 + (lane & 15) + k;
          af[m] = *(const bf16x8*)(xsb + rr * 128 + (ksub ^ ((rr & 7) << 4)));
        }
#pragma unroll
        for (int n = 0; n < 4; ++n) {
          const int c = wc * 64 + n * 16 + (lane & 15);
          bfx[n] =
              *(const bf16x8*)(bsb + c * 384 + k * 128 + (ksub ^ ((c & 7) << 4)));
        }
#pragma unroll
        for (int m = 0; m < 4; ++m)
#pragma unroll
          for (int n = 0; n < 4; ++n)
            acc[m][n] = __builtin_amdgcn_mfma_f32_16x16x32_bf16(
                af[m], bfx[n], acc[m][n], 0, 0, 0);
      }
    }
  }

  __syncthreads();
  float bc[4];
#pragma unroll
  for (int n = 0; n < 4; ++n) bc[n] = bias[wc * 64 + n * 16 + (lane & 15)];
#pragma unroll
  for (int m = 0; m < 4; ++m) {
#pragma unroll
    for (int n = 0; n < 4; ++n) {
      const int col = wc * 64 + n * 16 + (lane & 15);
#pragma unroll
      for (int r = 0; r < 4; ++r) {
        const int row = wr * 64 + m * 16 + ((lane >> 4) << 2) + r;
        float v = acc[m][n][r] + bc[n];
        v = v > 0.f ? v : 0.f;
        *(ushort*)(bsb + row * 256 + ((col * 2) ^ ((row & 7) << 4))) = f2bf(v);
      }
    }
  }
  __syncthreads();
  const int w = tid >> 6;
#pragma unroll
  for (int p = 0; p < 8; ++p) {
    const int rowb = p * 16 + w * 4 + (lane >> 4);
    const int colb = (lane & 15) * 16;
    uint4 v = *(const uint4*)(bsb + rowb * 256 + (colb ^ ((rowb & 7) << 4)));
    *(uint4*)((char*)(y + ((long)b * T_ + t0 + rowb) * 128) + colb) = v;
  }
}

// ---------------- LSTM scan with FUSED input projection --------------------
// 128 blocks (2 dir x 64 groups of 4 seqs), 4 waves, replica-spread nonlin
// (R12 structure). NEW: xg = w_ih @ y computed IN-SCAN as a shadow MFMA
// chain (bf16, K=128, bias as C-init) one step ahead of the recurrence --
// it depends only on y (prefetched 4 steps deep), so it issues in the idle
// slots (MfmaUtil was 8.5%). xg_gemm kernel + 134MB xgP buffer deleted.
// Critical path per step unchanged: ds_read h -> 2 f16 MFMA (C = AX_cur) ->
// replica-select -> merged-rcp nonlin -> ds_write + hout store -> barrier.
union UYB { uint4 u; bf16x8 b; };

#define AXBUILD(AXN, YFN)                                                      \
  do {                                                                         \
    UYB y0, y1, y2, y3;                                                        \
    y0.u = YFN[0];                                                             \
    y1.u = YFN[1];                                                             \
    y2.u = YFN[2];                                                             \
    y3.u = YFN[3];                                                             \
    _Pragma("unroll") for (int n = 0; n < 4; ++n) {                            \
      f32x4 a = __builtin_amdgcn_mfma_f32_16x16x32_bf16(wiA[n][0], y0.b,       \
                                                        biasC[n], 0, 0, 0);    \
      a = __builtin_amdgcn_mfma_f32_16x16x32_bf16(wiA[n][1], y1.b, a, 0, 0, 0);\
      a = __builtin_amdgcn_mfma_f32_16x16x32_bf16(wiA[n][2], y2.b, a, 0, 0, 0);\
      a = __builtin_amdgcn_mfma_f32_16x16x32_bf16(wiA[n][3], y3.b, a, 0, 0, 0);\
      AXN[n] = a;                                                              \
    }                                                                          \
  } while (0)

#define YLOAD(BUF, TT)                                                         \
  do {                                                                         \
    int tp = (TT);                                                             \
    tp = tp > T_ - 1 ? T_ - 1 : tp;                                            \
    const int ttp = dir ? (T_ - 1 - tp) : tp;                                  \
    _Pragma("unroll") for (int kk = 0; kk < 4; ++kk) BUF[kk] =                 \
        *(const uint4*)(ybase + (long)ttp * 256 + kk * 64);                    \
  } while (0)

#define LSTEP(J, AXC, AXN, YFN, YFL)                                           \
  do {                                                                         \
    const int t_ = t0ph + (J);                                                 \
    const int p_ = (J) & 1;                                                    \
    AXBUILD(AXN, YFN);     /* shadow: xg+bias for step t_+1 */                 \
    YLOAD(YFL, t_ + 4);    /* prefetch y for step t_+4 */                      \
    f16x8 bh0, bh1;                                                            \
    {                                                                          \
      const char* hb = hx + p_ * 576 + s * 144;                                \
      bh0 = *(const f16x8*)(hb + q * 16);                                      \
      bh1 = *(const f16x8*)(hb + 64 + q * 16);                                 \
    }                                                                          \
    f32x4 acc[4];                                                              \
    _Pragma("unroll") for (int n = 0; n < 4; ++n) {                            \
      acc[n] = __builtin_amdgcn_mfma_f32_16x16x32_f16(afA[n], bh0, AXC[n], 0,  \
                                                      0, 0);                   \
      acc[n] =                                                                 \
          __builtin_amdgcn_mfma_f32_16x16x32_f16(afB[n], bh1, acc[n], 0, 0, 0);\
    }                                                                          \
    float ge[4];                                                               \
    _Pragma("unroll") for (int e = 0; e < 4; ++e) {                            \
      float v01 = (r & 1) ? acc[1][e] : acc[0][e];                             \
      float v23 = (r & 1) ? acc[3][e] : acc[2][e];                             \
      ge[e] = (r & 2) ? v23 : v01;                                             \
    }                                                                          \
    float gi = ge[0], gf = ge[1], gg = ge[2], go = ge[3];                      \
    float Ei = __builtin_amdgcn_exp2f(gi);                                     \
    float Ef = __builtin_amdgcn_exp2f(gf);                                     \
    float Eg = __builtin_amdgcn_exp2f(gg);                                     \
    float Eo = __builtin_amdgcn_exp2f(go);                                     \
    float sf = __builtin_amdgcn_rcpf(1.f + Ef);                                \
    float den = __builtin_amdgcn_rcpf((1.f + Ei) * (1.f + Eg));                \
    cst = fmaf(sf, cst, (Eg - 1.f) * den);                                     \
    float Ec = __builtin_amdgcn_exp2f(SC_TANH * cst);                          \
    float hval = (Ec - 1.f) * __builtin_amdgcn_rcpf((1.f + Eo) * (1.f + Ec));  \
    const ushort hu = f2h(hval);                                               \
    *(ushort*)(hx + (1 - p_) * 576 + s * 144 + ub_) = hu;                      \
    {                                                                          \
      const int gt = dir ? (T_ - 1 - t_) : t_;                                 \
      houtp[(long)gt * 128] = hu;                                              \
    }                                                                          \
    asm volatile("s_waitcnt lgkmcnt(0)" ::: "memory");                         \
    __builtin_amdgcn_sched_barrier(0);                                         \
    __builtin_amdgcn_s_barrier();                                              \
    __builtin_amdgcn_sched_barrier(0);                                         \
  } while (0)

__global__ __launch_bounds__(256, 1) void lstm_seq_kernel(
    const ushort* __restrict__ whhP, const ushort* __restrict__ wiP2,
    const float* __restrict__ biasP2, const ushort* __restrict__ y,
    ushort* __restrict__ hout) {
  const int dir = blockIdx.x >> 6;
  const int bg = blockIdx.x & 63;
  const int tid = threadIdx.x;
  const int lane = tid & 63;
  const int w = tid >> 6;   // wave 0..3
  const int c = lane & 15;  // MFMA column
  const int q = lane >> 4;  // quarter
  const int s = c & 3;      // sequence within group (4 seqs)
  const int r = c >> 2;     // replica id = which unit this lane owns

  // h exchange: [parity][4 s][64 u] fp16, 144B row stride (conflict-free)
  __shared__ __align__(16) char hx[2 * 576];
  for (int i = tid; i < 288; i += 256) ((uint*)hx)[i] = 0u;

  // pinned A-frags (fp16 h-path): whhP rows 64w+16n+c, k [0,32),[32,64)
  f16x8 afA[4], afB[4];
  {
    const ushort* base = whhP + (long)dir * 256 * 64;
#pragma unroll
    for (int n = 0; n < 4; ++n) {
      const ushort* rp = base + (64 * w + 16 * n + c) * 64 + q * 8;
      afA[n] = *(const f16x8*)rp;
      afB[n] = *(const f16x8*)(rp + 32);
    }
  }
  // pinned A-frags (bf16 xg-path): wiP2 rows 64w+16n+c, K=128 in 4 chunks
  bf16x8 wiA[4][4];
  {
    const ushort* base2 = wiP2 + (long)dir * 256 * 128;
#pragma unroll
    for (int n = 0; n < 4; ++n)
#pragma unroll
      for (int kk = 0; kk < 4; ++kk)
        wiA[n][kk] = *(const bf16x8*)(base2 + (64 * w + 16 * n + c) * 128 +
                                      kk * 32 + q * 8);
  }
  // bias as MFMA C-init: rows 64w+16n+4q+e
  f32x4 biasC[4];
#pragma unroll
  for (int n = 0; n < 4; ++n)
    biasC[n] = *(const f32x4*)(biasP2 + dir * 256 + 64 * w + 16 * n + 4 * q);

  const int b = bg * 4 + s;
  const int u = 16 * w + 4 * q + r;  // this lane's unit
  const int ub_ = u * 2;             // byte offset within h row
  const char* ybase = (const char*)y + (long)b * T_ * 256 + q * 16;
  ushort* houtp = hout + (long)b * T_ * 128 + dir * 64 + u;

  float cst = 0.f;

  // y prefetch: 4 buffers, 4 steps deep (16B x 4 chunks per step per lane)
  uint4 YF0[4], YF1[4], YF2[4], YF3[4];
  YLOAD(YF0, 0);
  YLOAD(YF1, 1);
  YLOAD(YF2, 2);
  YLOAD(YF3, 3);
  // AX double-buffer: xg+bias accumulators (fp32), built one step ahead
  f32x4 AX0[4], AX1[4];
  AXBUILD(AX0, YF0);
  __syncthreads();

  for (int ph = 0; ph < 128; ++ph) {
    const int t0ph = ph * 4;
    LSTEP(0, AX0, AX1, YF1, YF0);
    LSTEP(1, AX1, AX0, YF2, YF1);
    LSTEP(2, AX0, AX1, YF3, YF2);
    LSTEP(3, AX1, AX0, YF0, YF3);
  }
}

// ---------------- Attention pool + LayerNorm + FC (fp16 hio) ---------------
__global__ __launch_bounds__(256) void head_kernel(
    const ushort* __restrict__ hio, const float* __restrict__ attn_w,
    const float* __restrict__ attn_b, const float* __restrict__ ln_g,
    const float* __restrict__ ln_b, const float* __restrict__ fc_w,
    const float* __restrict__ fc_b, float* __restrict__ res) {
  const int b = blockIdx.x;
  const int tid = threadIdx.x;
  __shared__ __align__(16) float aw[128];
  __shared__ float l[T_];
  __shared__ float red[16];
  __shared__ float pp[2][128];
  __shared__ float normed[128];
  if (tid < 128) aw[tid] = attn_w[tid];
  __syncthreads();
  const float ab = attn_b[0];

  for (int t = tid; t < T_; t += 256) {
    const ushort* row = hio + ((long)b * T_ + t) * 128;
    float a = ab;
#pragma unroll
    for (int d = 0; d < 128; d += 8) {
      uint4 v = *(const uint4*)(row + d);
      float2 p0 = __half22float2(*(const __half2*)&v.x);
      float2 p1 = __half22float2(*(const __half2*)&v.y);
      float2 p2 = __half22float2(*(const __half2*)&v.z);
      float2 p3 = __half22float2(*(const __half2*)&v.w);
      a += p0.x * aw[d] + p0.y * aw[d + 1] + p1.x * aw[d + 2] +
           p1.y * aw[d + 3] + p2.x * aw[d + 4] + p2.y * aw[d + 5] +
           p3.x * aw[d + 6] + p3.y * aw[d + 7];
    }
    l[t] = a;
  }
  __syncthreads();

  float v0 = l[tid], v1 = l[tid + 256];
  float m = fmaxf(v0, v1);
#pragma unroll
  for (int off = 32; off >= 1; off >>= 1) m = fmaxf(m, __shfl_xor(m, off));
  if ((tid & 63) == 0) red[tid >> 6] = m;
  __syncthreads();
  m = fmaxf(fmaxf(red[0], red[1]), fmaxf(red[2], red[3]));
  float e0 = __expf(v0 - m), e1 = __expf(v1 - m);
  float ssum = e0 + e1;
#pragma unroll
  for (int off = 32; off >= 1; off >>= 1) ssum += __shfl_xor(ssum, off);
  if ((tid & 63) == 0) red[4 + (tid >> 6)] = ssum;
  __syncthreads();
  float inv = 1.f / (red[4] + red[5] + red[6] + red[7]);
  l[tid] = e0 * inv;
  l[tid + 256] = e1 * inv;
  __syncthreads();

  const int d = tid & 127, half = tid >> 7;
  float p = 0.f;
  for (int t = half * 256; t < half * 256 + 256; ++t)
    p += l[t] * h2f(hio[((long)b * T_ + t) * 128 + d]);
  pp[half][d] = p;
  __syncthreads();

  if (tid < 128) {
    float pv = pp[0][tid] + pp[1][tid];
    float s1 = pv, s2 = pv * pv;
#pragma unroll
    for (int off = 32; off >= 1; off >>= 1) {
      s1 += __shfl_xor(s1, off);
      s2 += __shfl_xor(s2, off);
    }
    if ((tid & 63) == 0) {
      red[8 + (tid >> 6) * 2] = s1;
      red[9 + (tid >> 6) * 2] = s2;
    }
  }
  __syncthreads();
  if (tid < 128) {
    float s1 = red[8] + red[10], s2 = red[9] + red[11];
    float mu = s1 * (1.f / 128.f);
    float var = s2 * (1.f / 128.f) - mu * mu;
    float rinv = rsqrtf(var + 1e-5f);
    float pv = pp[0][tid] + pp[1][tid];
    normed[tid] = (pv - mu) * rinv * ln_g[tid] + ln_b[tid];
  }
  __syncthreads();

  if (tid < 2) {
    float a = fc_b[tid];
    for (int d2 = 0; d2 < 128; ++d2) a += normed[d2] * fc_w[tid * 128 + d2];
    res[b * 2 + tid] = a;
  }
}

extern "C" void kernel_launch(void* const* d_in, const int* in_sizes, int n_in,
                              void* d_out, int out_size, void* d_ws,
                              size_t ws_size, hipStream_t stream) {
  const float* x = (const float*)d_in[0];
  const float* conv_w = (const float*)d_in[1];
  const float* conv_b = (const float*)d_in[2];
  const float* w_ih_f = (const float*)d_in[3];
  const float* w_hh_f = (const float*)d_in[4];
  const float* b_f = (const float*)d_in[5];
  const float* w_ih_b = (const float*)d_in[6];
  const float* w_hh_b = (const float*)d_in[7];
  const float* b_b = (const float*)d_in[8];
  const float* attn_w = (const float*)d_in[9];
  const float* attn_b = (const float*)d_in[10];
  const float* ln_g = (const float*)d_in[11];
  const float* ln_b = (const float*)d_in[12];
  const float* fc_w = (const float*)d_in[13];
  const float* fc_b = (const float*)d_in[14];
  float* res = (float*)d_out;

  // ws layout (~68 MiB): xgP removed; hout no longer aliases y.
  char* ws = (char*)d_ws;
  ushort* wbT = (ushort*)ws;                       // 294,912 B
  ushort* wiP2 = (ushort*)(ws + 0x60000);          // 131,072 B (bf16, scaled)
  ushort* whhP = (ushort*)(ws + 0x80000);          // 65,536 B (fp16, scaled)
  float* biasP2 = (float*)(ws + 0x90000);          // 2,048 B (scaled)
  ushort* y = (ushort*)(ws + 0x100000);            // 33,554,432 B (bf16)
  ushort* hout = (ushort*)(ws + 0x100000 + 33554432);  // 33,554,432 B (fp16)

  pack_w_kernel<<<576, 256, 0, stream>>>(conv_w, wbT);
  pack_wiP2_kernel<<<256, 256, 0, stream>>>(w_ih_f, w_ih_b, wiP2);
  pack_whhP_kernel<<<128, 256, 0, stream>>>(w_hh_f, w_hh_b, whhP);
  pack_biasP2_kernel<<<2, 256, 0, stream>>>(b_f, b_b, biasP2);
  conv_gemm_kernel<<<B_ * (T_ / 128), 256, 0, stream>>>(x, wbT, conv_b, y);
  lstm_seq_kernel<<<128, 256, 0, stream>>>(whhP, wiP2, biasP2, y, hout);
  head_kernel<<<B_, 256, 0, stream>>>(hout, attn_w, attn_b, ln_g, ln_b, fc_w,
                                      fc_b, res);
}

// Round 14
// 318.426 us; speedup vs baseline: 1.0772x; 1.0772x over previous
//
#include <hip/hip_runtime.h>
#include <hip/hip_fp16.h>
#include <math.h>

typedef unsigned int uint;
typedef unsigned short ushort;

#define B_ 256
#define T_ 512
#define F_ 378
#define C_ 128
#define H_ 64
#define KPAD 1152   // 3 * 384

using f32x4 = __attribute__((ext_vector_type(4))) float;
using bf16x8 = __attribute__((ext_vector_type(8))) short;
using f16x8 = __attribute__((ext_vector_type(8))) _Float16;

__device__ __forceinline__ ushort f2bf(float f) {
  union { float f; uint u; } c; c.f = f;
  uint r = (c.u + 0x7fffu + ((c.u >> 16) & 1u)) >> 16;
  return (ushort)r;
}
__device__ __forceinline__ uint packbf2(float a, float b) {
  return (uint)f2bf(a) | (((uint)f2bf(b)) << 16);
}
__device__ __forceinline__ ushort f2h(float f) {
  __half h = __float2half(f);
  return *(ushort*)&h;
}
__device__ __forceinline__ float h2f(ushort u) {
  __half h;
  *(ushort*)&h = u;
  return __half2float(h);
}
#define SC_SIG -1.442695041f
#define SC_TANH 2.885390082f

// ---------------- pack conv w -> wbT[c][kk], kk = k*384+f, bf16 ------------
__global__ __launch_bounds__(256) void pack_w_kernel(
    const float* __restrict__ w, ushort* __restrict__ wbT) {
  int i = blockIdx.x * 256 + threadIdx.x;
  if (i >= C_ * KPAD) return;
  int c = i / KPAD, kk = i - c * KPAD;
  int k = kk / 384, f = kk - k * 384;
  float v = (f < F_) ? w[c * (F_ * 3) + f * 3 + k] : 0.f;
  wbT[i] = f2bf(v);
}

// ---- pack w_ih -> wP[dir][g''][128] bf16, PRE-SCALED (R12 g'' order) ------
// g'' = w*64 + q*16 + n*4 + e -> orig gate row e*64 + (16w + 4q + n).
__global__ __launch_bounds__(256) void pack_wiP_kernel(
    const float* __restrict__ wf, const float* __restrict__ wb,
    ushort* __restrict__ wP) {
  int i = blockIdx.x * 256 + threadIdx.x;  // 2*256*128 = 65536
  int dir = i >> 15, rem = i & 32767;
  int gp = rem >> 7, k = rem & 127;
  int e = gp & 3, n = (gp >> 2) & 3, q = (gp >> 4) & 3, w = gp >> 6;
  int u = 16 * w + 4 * q + n;
  const float* src = dir ? wb : wf;
  float scale = (e == 2) ? SC_TANH : SC_SIG;
  wP[i] = f2bf(src[(e * 64 + u) * 128 + k] * scale);
}

// ---- pack w_hh -> whhP[dir][r][64] FP16, PRE-SCALED (4-wave mapping) ------
__global__ __launch_bounds__(256) void pack_whhP_kernel(
    const float* __restrict__ wf, const float* __restrict__ wb,
    ushort* __restrict__ whhP) {
  int i = blockIdx.x * 256 + threadIdx.x;  // 2*256*64 = 32768
  if (i >= 32768) return;
  int dir = i >> 14, rem = i & 16383;
  int r = rem >> 6, k = rem & 63;
  int e = r & 3, q = (r >> 2) & 3, n = (r >> 4) & 3, w = r >> 6;
  int u = 16 * w + 4 * q + n;
  const float* src = dir ? wb : wf;
  float scale = (e == 2) ? SC_TANH : SC_SIG;
  whhP[i] = f2h(src[(e * 64 + u) * 64 + k] * scale);
}

// ---- pack bias -> biasP[dir][g''] fp32, same order+scale as wP ------------
__global__ __launch_bounds__(256) void pack_biasP_kernel(
    const float* __restrict__ bf, const float* __restrict__ bb,
    float* __restrict__ biasP) {
  int i = blockIdx.x * 256 + threadIdx.x;  // 512
  if (i >= 512) return;
  int dir = i >> 8, gp = i & 255;
  int e = gp & 3, n = (gp >> 2) & 3, q = (gp >> 4) & 3, w = gp >> 6;
  int u = 16 * w + 4 * q + n;
  const float* src = dir ? bb : bf;
  float scale = (e == 2) ? SC_TANH : SC_SIG;
  biasP[i] = src[e * 64 + u] * scale;
}

// ---------------- FUSED Conv1d + xg GEMM ----------------------------------
// Phase 1 (conv, unchanged structure): y tile [128t x 128c] via implicit
// GEMM, bias+ReLU, bf16 -> staged into bsb (swizzled 256B rows). y is NOT
// written to HBM (xg was its only consumer).
// Phase 2 (xg): 8 chunks of 64 g''-rows: stage wP chunk into xsb (16KB),
// xg[128t x 64g] = ytile @ wP^T (K=128, bias as MFMA C-init), LDS
// transpose, coalesced fp16 store to xgP. Runs at 8 waves/CU (2 blocks) --
// real MFMA/mem overlap, unlike the 1-wave/SIMD scan (R13 lesson).
__global__ __launch_bounds__(256, 2) void conv_xg_kernel(
    const float* __restrict__ x, const ushort* __restrict__ wbT,
    const float* __restrict__ bias, const ushort* __restrict__ wP,
    const float* __restrict__ biasP, ushort* __restrict__ xgP) {
  __shared__ __align__(16) char xsb[130 * 128];  // conv-A / wP chunk / out
  __shared__ __align__(16) char bsb[128 * 384];  // conv-B / y tile
  const int tid = threadIdx.x;
  const int lane = tid & 63;
  const int wr = (tid >> 7) & 1;
  const int wc = (tid >> 6) & 1;
  const int w = tid >> 6;
  const int b = blockIdx.x >> 2;
  const int t0 = (blockIdx.x & 3) << 7;

  f32x4 acc[4][4];
#pragma unroll
  for (int m = 0; m < 4; ++m)
#pragma unroll
    for (int n = 0; n < 4; ++n) acc[m][n] = (f32x4)(0.f);

  for (int fs = 0; fs < 6; ++fs) {
    __syncthreads();
    {
      auto stage_a = [&](int r, int h) {
        const int t = t0 - 1 + r;
        const bool ok = (t >= 0) && (t < T_);
        const float* srow = x + ((long)b * T_ + (ok ? t : 0)) * F_;
        const int fb = fs * 64 + h * 32;
        char* dst = xsb + r * 128;
        const int sw = (r & 7) << 4;
        uint pk[16];
        if (ok && fb + 31 < F_) {
#pragma unroll
          for (int j = 0; j < 16; ++j) {
            float2 v = *(const float2*)(srow + fb + 2 * j);
            pk[j] = packbf2(v.x, v.y);
          }
        } else {
#pragma unroll
          for (int j = 0; j < 16; ++j) {
            const int f = fb + 2 * j;
            float a = (ok && f < F_) ? srow[f] : 0.f;
            float c2 = (ok && f + 1 < F_) ? srow[f + 1] : 0.f;
            pk[j] = packbf2(a, c2);
          }
        }
#pragma unroll
        for (int j = 0; j < 4; ++j) {
          uint4 p = {pk[4 * j], pk[4 * j + 1], pk[4 * j + 2], pk[4 * j + 3]};
          *(uint4*)(dst + ((h * 64 + j * 16) ^ sw)) = p;
        }
      };
      stage_a(tid >> 1, tid & 1);
      if (tid < 4) stage_a(128 + (tid >> 1), tid & 1);
    }
    {
      const int c = tid >> 1, h = tid & 1;
      const ushort* src = wbT + c * KPAD + fs * 64 + h * 32;
      char* drow = bsb + c * 384;
      const int sw = (c & 7) << 4;
#pragma unroll
      for (int k = 0; k < 3; ++k)
#pragma unroll
        for (int j = 0; j < 4; ++j) {
          uint4 v = *(const uint4*)(src + k * 384 + j * 8);
          *(uint4*)(drow + k * 128 + ((h * 64 + j * 16) ^ sw)) = v;
        }
    }
    __syncthreads();

#pragma unroll
    for (int k = 0; k < 3; ++k) {
#pragma unroll
      for (int s = 0; s < 2; ++s) {
        bf16x8 af[4], bfx[4];
        const int ksub = s * 64 + ((lane >> 4) << 4);
#pragma unroll
        for (int m = 0; m < 4; ++m) {
          const int rr = wr * 64 + m * 16 + (lane & 15) + k;
          af[m] = *(const bf16x8*)(xsb + rr * 128 + (ksub ^ ((rr & 7) << 4)));
        }
#pragma unroll
        for (int n = 0; n < 4; ++n) {
          const int c = wc * 64 + n * 16 + (lane & 15);
          bfx[n] =
              *(const bf16x8*)(bsb + c * 384 + k * 128 + (ksub ^ ((c & 7) << 4)));
        }
#pragma unroll
        for (int m = 0; m < 4; ++m)
#pragma unroll
          for (int n = 0; n < 4; ++n)
            acc[m][n] = __builtin_amdgcn_mfma_f32_16x16x32_bf16(
                af[m], bfx[n], acc[m][n], 0, 0, 0);
      }
    }
  }

  // conv epilogue: bias+ReLU -> y tile (bf16, swizzled 256B rows) in bsb
  __syncthreads();
  {
    float bc[4];
#pragma unroll
    for (int n = 0; n < 4; ++n) bc[n] = bias[wc * 64 + n * 16 + (lane & 15)];
#pragma unroll
    for (int m = 0; m < 4; ++m) {
#pragma unroll
      for (int n = 0; n < 4; ++n) {
        const int col = wc * 64 + n * 16 + (lane & 15);
#pragma unroll
        for (int r = 0; r < 4; ++r) {
          const int row = wr * 64 + m * 16 + ((lane >> 4) << 2) + r;
          float v = acc[m][n][r] + bc[n];
          v = v > 0.f ? v : 0.f;
          *(ushort*)(bsb + row * 256 + ((col * 2) ^ ((row & 7) << 4))) =
              f2bf(v);
        }
      }
    }
  }

  // ---- phase 2: xg chunks. xg[t][g''] = y @ wP^T + biasP, fp16 ----
  const long m0 = (long)b * T_ + t0;
#pragma unroll 1
  for (int ch = 0; ch < 8; ++ch) {
    const int dirq = ch >> 2;
    const int g64 = ch & 3;
    const int gbase = dirq * 256 + g64 * 64;
    __syncthreads();  // xsb free (conv-A done / prev chunk store done)
    // stage wP rows gbase..gbase+63 into xsb (256B/row, swizzled)
    {
      const int r = tid >> 2, h4 = tid & 3;
      const ushort* src = wP + (long)(gbase + r) * 128 + h4 * 32;
      char* drow = xsb + r * 256;
      const int sw = (r & 7) << 4;
#pragma unroll
      for (int j = 0; j < 4; ++j) {
        uint4 v = *(const uint4*)(src + 8 * j);
        *(uint4*)(drow + ((h4 * 64 + j * 16) ^ sw)) = v;
      }
    }
    __syncthreads();
    // GEMM: wave w owns m-tiles {2w, 2w+1}; 4 n-tiles; K=128 (4 ks)
    f32x4 xacc[2][4];
#pragma unroll
    for (int n = 0; n < 4; ++n) {
      const float bcv = biasP[gbase + n * 16 + (lane & 15)];
      xacc[0][n] = (f32x4)(bcv);
      xacc[1][n] = (f32x4)(bcv);
    }
#pragma unroll
    for (int ks = 0; ks < 4; ++ks) {
      const int ksub = ks * 64 + ((lane >> 4) << 4);
      bf16x8 af[2], bfx[4];
#pragma unroll
      for (int mm = 0; mm < 2; ++mm) {
        const int rr = (w * 2 + mm) * 16 + (lane & 15);
        af[mm] = *(const bf16x8*)(bsb + rr * 256 + (ksub ^ ((rr & 7) << 4)));
      }
#pragma unroll
      for (int n = 0; n < 4; ++n) {
        const int rb = n * 16 + (lane & 15);
        bfx[n] = *(const bf16x8*)(xsb + rb * 256 + (ksub ^ ((rb & 7) << 4)));
      }
#pragma unroll
      for (int mm = 0; mm < 2; ++mm)
#pragma unroll
        for (int n = 0; n < 4; ++n)
          xacc[mm][n] = __builtin_amdgcn_mfma_f32_16x16x32_bf16(
              af[mm], bfx[n], xacc[mm][n], 0, 0, 0);
    }
    __syncthreads();  // done reading xsb as B
    // transpose into xsb: [128 t][128B] fp16, swizzled
#pragma unroll
    for (int mm = 0; mm < 2; ++mm) {
#pragma unroll
      for (int n = 0; n < 4; ++n) {
        const int col = n * 16 + (lane & 15);
#pragma unroll
        for (int r = 0; r < 4; ++r) {
          const int row = (w * 2 + mm) * 16 + ((lane >> 4) << 2) + r;
          *(ushort*)(xsb + row * 128 + ((col * 2) ^ ((row & 7) << 4))) =
              f2h(xacc[mm][n][r]);
        }
      }
    }
    __syncthreads();
    // coalesced store: 4 iters x 32 rows x 128B
    {
      const long dbase = (long)dirq * (B_ * T_);
#pragma unroll
      for (int it = 0; it < 4; ++it) {
        const int rowb = it * 32 + (tid >> 3);
        const int colb = (tid & 7) * 16;
        uint4 v = *(const uint4*)(xsb + rowb * 128 + (colb ^ ((rowb & 7) << 4)));
        *(uint4*)((char*)xgP + (dbase + m0 + rowb) * 512 + g64 * 128 + colb) =
            v;
      }
    }
  }
}

// ---------------- LSTM scan (R12 verbatim): replica-spread nonlin ----------
// 128 blocks (2 dir x 64 groups of 4 seqs), 4 waves. Lane (c=4r+s, q) owns
// unit 16w+4q+r; 1 unit/lane -> 8 trans-ops/wave-step. h exchange via LDS
// 144B-stride rows (conflict-free). Merged-rcp nonlin, pre-scaled weights.
union U2 { uint u; __half2 h2; };

#define LSTEP(J, XR)                                                           \
  do {                                                                         \
    const int t_ = t0ph + (J);                                                 \
    const int p_ = t_ & 1;                                                     \
    const uint2 cur = XR;                                                      \
    {                                                                          \
      int tp = t_ + 4;                                                         \
      tp = tp > T_ - 1 ? T_ - 1 : tp;                                          \
      const int ttp = dir ? (T_ - 1 - tp) : tp;                                \
      XR = *(const uint2*)(xgbase + (long)ttp * 512);                          \
    }                                                                          \
    f16x8 bh0, bh1;                                                            \
    {                                                                          \
      const char* hb = hx + p_ * 576 + s * 144;                                \
      bh0 = *(const f16x8*)(hb + q * 16);                                      \
      bh1 = *(const f16x8*)(hb + 64 + q * 16);                                 \
    }                                                                          \
    f32x4 acc[4];                                                              \
    _Pragma("unroll") for (int n = 0; n < 4; ++n) {                            \
      acc[n] = __builtin_amdgcn_mfma_f32_16x16x32_f16(afA[n], bh0,             \
                                                      (f32x4)(0.f), 0, 0, 0);  \
      acc[n] =                                                                 \
          __builtin_amdgcn_mfma_f32_16x16x32_f16(afB[n], bh1, acc[n], 0, 0, 0);\
    }                                                                          \
    float ge[4];                                                               \
    _Pragma("unroll") for (int e = 0; e < 4; ++e) {                            \
      float v01 = (r & 1) ? acc[1][e] : acc[0][e];                             \
      float v23 = (r & 1) ? acc[3][e] : acc[2][e];                             \
      ge[e] = (r & 2) ? v23 : v01;                                             \
    }                                                                          \
    U2 ua, ub;                                                                 \
    ua.u = cur.x;                                                              \
    ub.u = cur.y;                                                              \
    float2 xif = __half22float2(ua.h2);                                        \
    float2 xgo = __half22float2(ub.h2);                                        \
    float gi = ge[0] + xif.x, gf = ge[1] + xif.y;                              \
    float gg = ge[2] + xgo.x, go = ge[3] + xgo.y;                              \
    float Ei = __builtin_amdgcn_exp2f(gi);                                     \
    float Ef = __builtin_amdgcn_exp2f(gf);                                     \
    float Eg = __builtin_amdgcn_exp2f(gg);                                     \
    float Eo = __builtin_amdgcn_exp2f(go);                                     \
    float sf = __builtin_amdgcn_rcpf(1.f + Ef);                                \
    float den = __builtin_amdgcn_rcpf((1.f + Ei) * (1.f + Eg));                \
    cst = fmaf(sf, cst, (Eg - 1.f) * den);                                     \
    float Ec = __builtin_amdgcn_exp2f(SC_TANH * cst);                          \
    float hval = (Ec - 1.f) * __builtin_amdgcn_rcpf((1.f + Eo) * (1.f + Ec));  \
    const ushort hu = f2h(hval);                                               \
    *(ushort*)(hx + (1 - p_) * 576 + s * 144 + ub_) = hu;                      \
    {                                                                          \
      const int gt = dir ? (T_ - 1 - t_) : t_;                                 \
      houtp[(long)gt * 128] = hu;                                              \
    }                                                                          \
    asm volatile("s_waitcnt lgkmcnt(0)" ::: "memory");                         \
    __builtin_amdgcn_sched_barrier(0);                                         \
    __builtin_amdgcn_s_barrier();                                              \
    __builtin_amdgcn_sched_barrier(0);                                         \
  } while (0)

__global__ __launch_bounds__(256, 1) void lstm_seq_kernel(
    const ushort* __restrict__ whhP, const ushort* __restrict__ xgP,
    ushort* __restrict__ hout) {
  const int dir = blockIdx.x >> 6;
  const int bg = blockIdx.x & 63;
  const int tid = threadIdx.x;
  const int lane = tid & 63;
  const int w = tid >> 6;   // wave 0..3
  const int c = lane & 15;  // MFMA column
  const int q = lane >> 4;  // quarter
  const int s = c & 3;      // sequence within group (4 seqs)
  const int r = c >> 2;     // replica id = which unit this lane owns

  __shared__ __align__(16) char hx[2 * 576];
  for (int i = tid; i < 288; i += 256) ((uint*)hx)[i] = 0u;

  f16x8 afA[4], afB[4];
  {
    const ushort* base = whhP + (long)dir * 256 * 64;
#pragma unroll
    for (int n = 0; n < 4; ++n) {
      const ushort* rp = base + (64 * w + 16 * n + c) * 64 + q * 8;
      afA[n] = *(const f16x8*)rp;
      afB[n] = *(const f16x8*)(rp + 32);
    }
  }

  const int b = bg * 4 + s;
  const int u = 16 * w + 4 * q + r;
  const int ub_ = u * 2;
  const char* xgbase = (const char*)xgP + (((long)dir * B_ + b) * T_) * 512 +
                       w * 128 + q * 32 + r * 8;
  ushort* houtp = hout + (long)b * T_ * 128 + dir * 64 + u;

  float cst = 0.f;

  uint2 x0, x1, x2, x3;
  {
    x0 = *(const uint2*)(xgbase + (long)(dir ? T_ - 1 : 0) * 512);
    x1 = *(const uint2*)(xgbase + (long)(dir ? T_ - 2 : 1) * 512);
    x2 = *(const uint2*)(xgbase + (long)(dir ? T_ - 3 : 2) * 512);
    x3 = *(const uint2*)(xgbase + (long)(dir ? T_ - 4 : 3) * 512);
  }
  __syncthreads();

  for (int ph = 0; ph < 128; ++ph) {
    const int t0ph = ph * 4;
    LSTEP(0, x0);
    LSTEP(1, x1);
    LSTEP(2, x2);
    LSTEP(3, x3);
  }
}

// ---------------- Attention pool + LayerNorm + FC (fp16 hio) ---------------
__global__ __launch_bounds__(256) void head_kernel(
    const ushort* __restrict__ hio, const float* __restrict__ attn_w,
    const float* __restrict__ attn_b, const float* __restrict__ ln_g,
    const float* __restrict__ ln_b, const float* __restrict__ fc_w,
    const float* __restrict__ fc_b, float* __restrict__ res) {
  const int b = blockIdx.x;
  const int tid = threadIdx.x;
  __shared__ __align__(16) float aw[128];
  __shared__ float l[T_];
  __shared__ float red[16];
  __shared__ float pp[2][128];
  __shared__ float normed[128];
  if (tid < 128) aw[tid] = attn_w[tid];
  __syncthreads();
  const float ab = attn_b[0];

  for (int t = tid; t < T_; t += 256) {
    const ushort* row = hio + ((long)b * T_ + t) * 128;
    float a = ab;
#pragma unroll
    for (int d = 0; d < 128; d += 8) {
      uint4 v = *(const uint4*)(row + d);
      float2 p0 = __half22float2(*(const __half2*)&v.x);
      float2 p1 = __half22float2(*(const __half2*)&v.y);
      float2 p2 = __half22float2(*(const __half2*)&v.z);
      float2 p3 = __half22float2(*(const __half2*)&v.w);
      a += p0.x * aw[d] + p0.y * aw[d + 1] + p1.x * aw[d + 2] +
           p1.y * aw[d + 3] + p2.x * aw[d + 4] + p2.y * aw[d + 5] +
           p3.x * aw[d + 6] + p3.y * aw[d + 7];
    }
    l[t] = a;
  }
  __syncthreads();

  float v0 = l[tid], v1 = l[tid + 256];
  float m = fmaxf(v0, v1);
#pragma unroll
  for (int off = 32; off >= 1; off >>= 1) m = fmaxf(m, __shfl_xor(m, off));
  if ((tid & 63) == 0) red[tid >> 6] = m;
  __syncthreads();
  m = fmaxf(fmaxf(red[0], red[1]), fmaxf(red[2], red[3]));
  float e0 = __expf(v0 - m), e1 = __expf(v1 - m);
  float ssum = e0 + e1;
#pragma unroll
  for (int off = 32; off >= 1; off >>= 1) ssum += __shfl_xor(ssum, off);
  if ((tid & 63) == 0) red[4 + (tid >> 6)] = ssum;
  __syncthreads();
  float inv = 1.f / (red[4] + red[5] + red[6] + red[7]);
  l[tid] = e0 * inv;
  l[tid + 256] = e1 * inv;
  __syncthreads();

  const int d = tid & 127, half = tid >> 7;
  float p = 0.f;
  for (int t = half * 256; t < half * 256 + 256; ++t)
    p += l[t] * h2f(hio[((long)b * T_ + t) * 128 + d]);
  pp[half][d] = p;
  __syncthreads();

  if (tid < 128) {
    float pv = pp[0][tid] + pp[1][tid];
    float s1 = pv, s2 = pv * pv;
#pragma unroll
    for (int off = 32; off >= 1; off >>= 1) {
      s1 += __shfl_xor(s1, off);
      s2 += __shfl_xor(s2, off);
    }
    if ((tid & 63) == 0) {
      red[8 + (tid >> 6) * 2] = s1;
      red[9 + (tid >> 6) * 2] = s2;
    }
  }
  __syncthreads();
  if (tid < 128) {
    float s1 = red[8] + red[10], s2 = red[9] + red[11];
    float mu = s1 * (1.f / 128.f);
    float var = s2 * (1.f / 128.f) - mu * mu;
    float rinv = rsqrtf(var + 1e-5f);
    float pv = pp[0][tid] + pp[1][tid];
    normed[tid] = (pv - mu) * rinv * ln_g[tid] + ln_b[tid];
  }
  __syncthreads();

  if (tid < 2) {
    float a = fc_b[tid];
    for (int d2 = 0; d2 < 128; ++d2) a += normed[d2] * fc_w[tid * 128 + d2];
    res[b * 2 + tid] = a;
  }
}

extern "C" void kernel_launch(void* const* d_in, const int* in_sizes, int n_in,
                              void* d_out, int out_size, void* d_ws,
                              size_t ws_size, hipStream_t stream) {
  const float* x = (const float*)d_in[0];
  const float* conv_w = (const float*)d_in[1];
  const float* conv_b = (const float*)d_in[2];
  const float* w_ih_f = (const float*)d_in[3];
  const float* w_hh_f = (const float*)d_in[4];
  const float* b_f = (const float*)d_in[5];
  const float* w_ih_b = (const float*)d_in[6];
  const float* w_hh_b = (const float*)d_in[7];
  const float* b_b = (const float*)d_in[8];
  const float* attn_w = (const float*)d_in[9];
  const float* attn_b = (const float*)d_in[10];
  const float* ln_g = (const float*)d_in[11];
  const float* ln_b = (const float*)d_in[12];
  const float* fc_w = (const float*)d_in[13];
  const float* fc_b = (const float*)d_in[14];
  float* res = (float*)d_out;

  // ws layout (~169 MiB): y buffer deleted (xg produced directly by conv).
  char* ws = (char*)d_ws;
  ushort* wbT = (ushort*)ws;                       // 294,912 B
  ushort* wP = (ushort*)(ws + 0x60000);            // 131,072 B (bf16, scaled)
  ushort* whhP = (ushort*)(ws + 0x80000);          // 65,536 B (fp16, scaled)
  float* biasP = (float*)(ws + 0x90000);           // 2,048 B (scaled)
  ushort* xgP = (ushort*)(ws + 0x100000);          // 134,217,728 B (fp16)
  ushort* hout = (ushort*)(ws + 0x100000 + 134217728);  // 33,554,432 B (fp16)

  pack_w_kernel<<<576, 256, 0, stream>>>(conv_w, wbT);
  pack_wiP_kernel<<<256, 256, 0, stream>>>(w_ih_f, w_ih_b, wP);
  pack_whhP_kernel<<<128, 256, 0, stream>>>(w_hh_f, w_hh_b, whhP);
  pack_biasP_kernel<<<2, 256, 0, stream>>>(b_f, b_b, biasP);
  conv_xg_kernel<<<B_ * (T_ / 128), 256, 0, stream>>>(x, wbT, conv_b, wP,
                                                      biasP, xgP);
  lstm_seq_kernel<<<128, 256, 0, stream>>>(whhP, xgP, hout);
  head_kernel<<<B_, 256, 0, stream>>>(hout, attn_w, attn_b, ln_g, ln_b, fc_w,
                                      fc_b, res);
}

// Round 15
// 301.636 us; speedup vs baseline: 1.1372x; 1.0557x over previous
//
#include <hip/hip_runtime.h>
#include <hip/hip_fp16.h>
#include <math.h>

typedef unsigned int uint;
typedef unsigned short ushort;

#define B_ 256
#define T_ 512
#define F_ 378
#define C_ 128
#define H_ 64
#define KPAD 1152   // 3 * 384

using f32x4 = __attribute__((ext_vector_type(4))) float;
using bf16x8 = __attribute__((ext_vector_type(8))) short;
using f16x8 = __attribute__((ext_vector_type(8))) _Float16;

__device__ __forceinline__ ushort f2bf(float f) {
  union { float f; uint u; } c; c.f = f;
  uint r = (c.u + 0x7fffu + ((c.u >> 16) & 1u)) >> 16;
  return (ushort)r;
}
__device__ __forceinline__ uint packbf2(float a, float b) {
  return (uint)f2bf(a) | (((uint)f2bf(b)) << 16);
}
__device__ __forceinline__ ushort f2h(float f) {
  __half h = __float2half(f);
  return *(ushort*)&h;
}
__device__ __forceinline__ float h2f(ushort u) {
  __half h;
  *(ushort*)&h = u;
  return __half2float(h);
}
#define SC_SIG -1.442695041f
#define SC_TANH 2.885390082f

// ---------------- pack conv w -> wbT[c][kk], kk = k*384+f, bf16 ------------
__global__ __launch_bounds__(256) void pack_w_kernel(
    const float* __restrict__ w, ushort* __restrict__ wbT) {
  int i = blockIdx.x * 256 + threadIdx.x;
  if (i >= C_ * KPAD) return;
  int c = i / KPAD, kk = i - c * KPAD;
  int k = kk / 384, f = kk - k * 384;
  float v = (f < F_) ? w[c * (F_ * 3) + f * 3 + k] : 0.f;
  wbT[i] = f2bf(v);
}

// ---- pack w_ih -> wP[dir][g''][128] bf16, PRE-SCALED (R12 g'' order) ------
__global__ __launch_bounds__(256) void pack_wiP_kernel(
    const float* __restrict__ wf, const float* __restrict__ wb,
    ushort* __restrict__ wP) {
  int i = blockIdx.x * 256 + threadIdx.x;  // 2*256*128 = 65536
  int dir = i >> 15, rem = i & 32767;
  int gp = rem >> 7, k = rem & 127;
  int e = gp & 3, n = (gp >> 2) & 3, q = (gp >> 4) & 3, w = gp >> 6;
  int u = 16 * w + 4 * q + n;
  const float* src = dir ? wb : wf;
  float scale = (e == 2) ? SC_TANH : SC_SIG;
  wP[i] = f2bf(src[(e * 64 + u) * 128 + k] * scale);
}

// ---- pack w_hh -> whhP[dir][r][64] FP16, PRE-SCALED (4-wave mapping) ------
__global__ __launch_bounds__(256) void pack_whhP_kernel(
    const float* __restrict__ wf, const float* __restrict__ wb,
    ushort* __restrict__ whhP) {
  int i = blockIdx.x * 256 + threadIdx.x;  // 2*256*64 = 32768
  if (i >= 32768) return;
  int dir = i >> 14, rem = i & 16383;
  int r = rem >> 6, k = rem & 63;
  int e = r & 3, q = (r >> 2) & 3, n = (r >> 4) & 3, w = r >> 6;
  int u = 16 * w + 4 * q + n;
  const float* src = dir ? wb : wf;
  float scale = (e == 2) ? SC_TANH : SC_SIG;
  whhP[i] = f2h(src[(e * 64 + u) * 64 + k] * scale);
}

// ---- pack bias -> biasP[dir][g''] fp32, same order+scale as wP ------------
__global__ __launch_bounds__(256) void pack_biasP_kernel(
    const float* __restrict__ bf, const float* __restrict__ bb,
    float* __restrict__ biasP) {
  int i = blockIdx.x * 256 + threadIdx.x;  // 512
  if (i >= 512) return;
  int dir = i >> 8, gp = i & 255;
  int e = gp & 3, n = (gp >> 2) & 3, q = (gp >> 4) & 3, w = gp >> 6;
  int u = 16 * w + 4 * q + n;
  const float* src = dir ? bb : bf;
  float scale = (e == 2) ? SC_TANH : SC_SIG;
  biasP[i] = src[e * 64 + u] * scale;
}

// ---------------- FUSED Conv1d + xg GEMM ----------------------------------
// Phase 1: conv via implicit GEMM -> y tile bf16 staged in bsb[0:32K).
// Phase 2: 8 chunks x {stage wP (xsb), MFMA (bias C-init), transpose ->
// bsb[32K:48K), store}. 3 barriers/chunk (transpose buffer disjoint from
// xsb lets {MFMA-done, store-done} share one sync).
__global__ __launch_bounds__(256, 2) void conv_xg_kernel(
    const float* __restrict__ x, const ushort* __restrict__ wbT,
    const float* __restrict__ bias, const ushort* __restrict__ wP,
    const float* __restrict__ biasP, ushort* __restrict__ xgP) {
  __shared__ __align__(16) char xsb[130 * 128];  // conv-A / wP chunk
  __shared__ __align__(16) char bsb[128 * 384];  // conv-B / y tile / out
  const int tid = threadIdx.x;
  const int lane = tid & 63;
  const int wr = (tid >> 7) & 1;
  const int wc = (tid >> 6) & 1;
  const int w = tid >> 6;
  const int b = blockIdx.x >> 2;
  const int t0 = (blockIdx.x & 3) << 7;

  f32x4 acc[4][4];
#pragma unroll
  for (int m = 0; m < 4; ++m)
#pragma unroll
    for (int n = 0; n < 4; ++n) acc[m][n] = (f32x4)(0.f);

  for (int fs = 0; fs < 6; ++fs) {
    __syncthreads();
    {
      auto stage_a = [&](int r, int h) {
        const int t = t0 - 1 + r;
        const bool ok = (t >= 0) && (t < T_);
        const float* srow = x + ((long)b * T_ + (ok ? t : 0)) * F_;
        const int fb = fs * 64 + h * 32;
        char* dst = xsb + r * 128;
        const int sw = (r & 7) << 4;
        uint pk[16];
        if (ok && fb + 31 < F_) {
#pragma unroll
          for (int j = 0; j < 16; ++j) {
            float2 v = *(const float2*)(srow + fb + 2 * j);
            pk[j] = packbf2(v.x, v.y);
          }
        } else {
#pragma unroll
          for (int j = 0; j < 16; ++j) {
            const int f = fb + 2 * j;
            float a = (ok && f < F_) ? srow[f] : 0.f;
            float c2 = (ok && f + 1 < F_) ? srow[f + 1] : 0.f;
            pk[j] = packbf2(a, c2);
          }
        }
#pragma unroll
        for (int j = 0; j < 4; ++j) {
          uint4 p = {pk[4 * j], pk[4 * j + 1], pk[4 * j + 2], pk[4 * j + 3]};
          *(uint4*)(dst + ((h * 64 + j * 16) ^ sw)) = p;
        }
      };
      stage_a(tid >> 1, tid & 1);
      if (tid < 4) stage_a(128 + (tid >> 1), tid & 1);
    }
    {
      const int c = tid >> 1, h = tid & 1;
      const ushort* src = wbT + c * KPAD + fs * 64 + h * 32;
      char* drow = bsb + c * 384;
      const int sw = (c & 7) << 4;
#pragma unroll
      for (int k = 0; k < 3; ++k)
#pragma unroll
        for (int j = 0; j < 4; ++j) {
          uint4 v = *(const uint4*)(src + k * 384 + j * 8);
          *(uint4*)(drow + k * 128 + ((h * 64 + j * 16) ^ sw)) = v;
        }
    }
    __syncthreads();

#pragma unroll
    for (int k = 0; k < 3; ++k) {
#pragma unroll
      for (int s = 0; s < 2; ++s) {
        bf16x8 af[4], bfx[4];
        const int ksub = s * 64 + ((lane >> 4) << 4);
#pragma unroll
        for (int m = 0; m < 4; ++m) {
          const int rr = wr * 64 + m * 16 + (lane & 15) + k;
          af[m] = *(const bf16x8*)(xsb + rr * 128 + (ksub ^ ((rr & 7) << 4)));
        }
#pragma unroll
        for (int n = 0; n < 4; ++n) {
          const int c = wc * 64 + n * 16 + (lane & 15);
          bfx[n] =
              *(const bf16x8*)(bsb + c * 384 + k * 128 + (ksub ^ ((c & 7) << 4)));
        }
#pragma unroll
        for (int m = 0; m < 4; ++m)
#pragma unroll
          for (int n = 0; n < 4; ++n)
            acc[m][n] = __builtin_amdgcn_mfma_f32_16x16x32_bf16(
                af[m], bfx[n], acc[m][n], 0, 0, 0);
      }
    }
  }

  // conv epilogue: bias+ReLU -> y tile (bf16, swizzled 256B rows) in bsb
  __syncthreads();
  {
    float bc[4];
#pragma unroll
    for (int n = 0; n < 4; ++n) bc[n] = bias[wc * 64 + n * 16 + (lane & 15)];
#pragma unroll
    for (int m = 0; m < 4; ++m) {
#pragma unroll
      for (int n = 0; n < 4; ++n) {
        const int col = wc * 64 + n * 16 + (lane & 15);
#pragma unroll
        for (int r = 0; r < 4; ++r) {
          const int row = wr * 64 + m * 16 + ((lane >> 4) << 2) + r;
          float v = acc[m][n][r] + bc[n];
          v = v > 0.f ? v : 0.f;
          *(ushort*)(bsb + row * 256 + ((col * 2) ^ ((row & 7) << 4))) =
              f2bf(v);
        }
      }
    }
  }

  // ---- phase 2: xg chunks. xg[t][g''] = y @ wP^T + biasP, fp16 ----
  const long m0 = (long)b * T_ + t0;
  char* const tbuf = bsb + 32768;  // 16KB transpose buffer (disjoint)
#pragma unroll 1
  for (int ch = 0; ch < 8; ++ch) {
    const int dirq = ch >> 2;
    const int g64 = ch & 3;
    const int gbase = dirq * 256 + g64 * 64;
    __syncthreads();  // prev MFMA done reading xsb; prev store done (tbuf)
    // stage wP rows gbase..gbase+63 into xsb (256B/row, swizzled)
    {
      const int r = tid >> 2, h4 = tid & 3;
      const ushort* src = wP + (long)(gbase + r) * 128 + h4 * 32;
      char* drow = xsb + r * 256;
      const int sw = (r & 7) << 4;
#pragma unroll
      for (int j = 0; j < 4; ++j) {
        uint4 v = *(const uint4*)(src + 8 * j);
        *(uint4*)(drow + ((h4 * 64 + j * 16) ^ sw)) = v;
      }
    }
    __syncthreads();  // wP ready
    // GEMM: wave w owns m-tiles {2w, 2w+1}; 4 n-tiles; K=128 (4 ks)
    f32x4 xacc[2][4];
#pragma unroll
    for (int n = 0; n < 4; ++n) {
      const float bcv = biasP[gbase + n * 16 + (lane & 15)];
      xacc[0][n] = (f32x4)(bcv);
      xacc[1][n] = (f32x4)(bcv);
    }
#pragma unroll
    for (int ks = 0; ks < 4; ++ks) {
      const int ksub = ks * 64 + ((lane >> 4) << 4);
      bf16x8 af[2], bfx[4];
#pragma unroll
      for (int mm = 0; mm < 2; ++mm) {
        const int rr = (w * 2 + mm) * 16 + (lane & 15);
        af[mm] = *(const bf16x8*)(bsb + rr * 256 + (ksub ^ ((rr & 7) << 4)));
      }
#pragma unroll
      for (int n = 0; n < 4; ++n) {
        const int rb = n * 16 + (lane & 15);
        bfx[n] = *(const bf16x8*)(xsb + rb * 256 + (ksub ^ ((rb & 7) << 4)));
      }
#pragma unroll
      for (int mm = 0; mm < 2; ++mm)
#pragma unroll
        for (int n = 0; n < 4; ++n)
          xacc[mm][n] = __builtin_amdgcn_mfma_f32_16x16x32_bf16(
              af[mm], bfx[n], xacc[mm][n], 0, 0, 0);
    }
    // transpose into tbuf: [128 t][128B] fp16, swizzled (no sync needed
    // before: tbuf was drained by the sync at loop top)
#pragma unroll
    for (int mm = 0; mm < 2; ++mm) {
#pragma unroll
      for (int n = 0; n < 4; ++n) {
        const int col = n * 16 + (lane & 15);
#pragma unroll
        for (int r = 0; r < 4; ++r) {
          const int row = (w * 2 + mm) * 16 + ((lane >> 4) << 2) + r;
          *(ushort*)(tbuf + row * 128 + ((col * 2) ^ ((row & 7) << 4))) =
              f2h(xacc[mm][n][r]);
        }
      }
    }
    __syncthreads();  // transpose visible
    // coalesced store: 4 iters x 32 rows x 128B
    {
      const long dbase = (long)dirq * (B_ * T_);
#pragma unroll
      for (int it = 0; it < 4; ++it) {
        const int rowb = it * 32 + (tid >> 3);
        const int colb = (tid & 7) * 16;
        uint4 v =
            *(const uint4*)(tbuf + rowb * 128 + (colb ^ ((rowb & 7) << 4)));
        *(uint4*)((char*)xgP + (dbase + m0 + rowb) * 512 + g64 * 128 + colb) =
            v;
      }
    }
  }
}

// ---------------- LSTM scan (R12 structure, 8-deep xg prefetch) ------------
// 128 blocks (2 dir x 64 groups of 4 seqs), 4 waves. Lane (c=4r+s, q) owns
// unit 16w+4q+r; 1 unit/lane -> 8 trans-ops/wave-step. h exchange via LDS
// 144B-stride rows (conflict-free). Merged-rcp nonlin, pre-scaled weights.
// 8-deep prefetch covers ~6700cy -- hides cold-HBM xg misses (R14: conv_xg's
// x streaming evicts early xgP tiles from L3).
union U2 { uint u; __half2 h2; };

#define LSTEP(J, XR)                                                           \
  do {                                                                         \
    const int t_ = t0ph + (J);                                                 \
    const int p_ = t_ & 1;                                                     \
    const uint2 cur = XR;                                                      \
    {                                                                          \
      int tp = t_ + 8;                                                         \
      tp = tp > T_ - 1 ? T_ - 1 : tp;                                          \
      const int ttp = dir ? (T_ - 1 - tp) : tp;                                \
      XR = *(const uint2*)(xgbase + (long)ttp * 512);                          \
    }                                                                          \
    f16x8 bh0, bh1;                                                            \
    {                                                                          \
      const char* hb = hx + p_ * 576 + s * 144;                                \
      bh0 = *(const f16x8*)(hb + q * 16);                                      \
      bh1 = *(const f16x8*)(hb + 64 + q * 16);                                 \
    }                                                                          \
    f32x4 acc[4];                                                              \
    _Pragma("unroll") for (int n = 0; n < 4; ++n) {                            \
      acc[n] = __builtin_amdgcn_mfma_f32_16x16x32_f16(afA[n], bh0,             \
                                                      (f32x4)(0.f), 0, 0, 0);  \
      acc[n] =                                                                 \
          __builtin_amdgcn_mfma_f32_16x16x32_f16(afB[n], bh1, acc[n], 0, 0, 0);\
    }                                                                          \
    float ge[4];                                                               \
    _Pragma("unroll") for (int e = 0; e < 4; ++e) {                            \
      float v01 = (r & 1) ? acc[1][e] : acc[0][e];                             \
      float v23 = (r & 1) ? acc[3][e] : acc[2][e];                             \
      ge[e] = (r & 2) ? v23 : v01;                                             \
    }                                                                          \
    U2 ua, ub;                                                                 \
    ua.u = cur.x;                                                              \
    ub.u = cur.y;                                                              \
    float2 xif = __half22float2(ua.h2);                                        \
    float2 xgo = __half22float2(ub.h2);                                        \
    float gi = ge[0] + xif.x, gf = ge[1] + xif.y;                              \
    float gg = ge[2] + xgo.x, go = ge[3] + xgo.y;                              \
    float Ei = __builtin_amdgcn_exp2f(gi);                                     \
    float Ef = __builtin_amdgcn_exp2f(gf);                                     \
    float Eg = __builtin_amdgcn_exp2f(gg);                                     \
    float Eo = __builtin_amdgcn_exp2f(go);                                     \
    float sf = __builtin_amdgcn_rcpf(1.f + Ef);                                \
    float den = __builtin_amdgcn_rcpf((1.f + Ei) * (1.f + Eg));                \
    cst = fmaf(sf, cst, (Eg - 1.f) * den);                                     \
    float Ec = __builtin_amdgcn_exp2f(SC_TANH * cst);                          \
    float hval = (Ec - 1.f) * __builtin_amdgcn_rcpf((1.f + Eo) * (1.f + Ec));  \
    const ushort hu = f2h(hval);                                               \
    *(ushort*)(hx + (1 - p_) * 576 + s * 144 + ub_) = hu;                      \
    {                                                                          \
      const int gt = dir ? (T_ - 1 - t_) : t_;                                 \
      houtp[(long)gt * 128] = hu;                                              \
    }                                                                          \
    asm volatile("s_waitcnt lgkmcnt(0)" ::: "memory");                         \
    __builtin_amdgcn_sched_barrier(0);                                         \
    __builtin_amdgcn_s_barrier();                                              \
    __builtin_amdgcn_sched_barrier(0);                                         \
  } while (0)

__global__ __launch_bounds__(256, 1) void lstm_seq_kernel(
    const ushort* __restrict__ whhP, const ushort* __restrict__ xgP,
    ushort* __restrict__ hout) {
  const int dir = blockIdx.x >> 6;
  const int bg = blockIdx.x & 63;
  const int tid = threadIdx.x;
  const int lane = tid & 63;
  const int w = tid >> 6;   // wave 0..3
  const int c = lane & 15;  // MFMA column
  const int q = lane >> 4;  // quarter
  const int s = c & 3;      // sequence within group (4 seqs)
  const int r = c >> 2;     // replica id = which unit this lane owns

  __shared__ __align__(16) char hx[2 * 576];
  for (int i = tid; i < 288; i += 256) ((uint*)hx)[i] = 0u;

  f16x8 afA[4], afB[4];
  {
    const ushort* base = whhP + (long)dir * 256 * 64;
#pragma unroll
    for (int n = 0; n < 4; ++n) {
      const ushort* rp = base + (64 * w + 16 * n + c) * 64 + q * 8;
      afA[n] = *(const f16x8*)rp;
      afB[n] = *(const f16x8*)(rp + 32);
    }
  }

  const int b = bg * 4 + s;
  const int u = 16 * w + 4 * q + r;
  const int ub_ = u * 2;
  const char* xgbase = (const char*)xgP + (((long)dir * B_ + b) * T_) * 512 +
                       w * 128 + q * 32 + r * 8;
  ushort* houtp = hout + (long)b * T_ * 128 + dir * 64 + u;

  float cst = 0.f;

  // 8-deep xg prefetch (8B/step/lane)
  uint2 x0, x1, x2, x3, x4, x5, x6, x7;
  {
    x0 = *(const uint2*)(xgbase + (long)(dir ? T_ - 1 : 0) * 512);
    x1 = *(const uint2*)(xgbase + (long)(dir ? T_ - 2 : 1) * 512);
    x2 = *(const uint2*)(xgbase + (long)(dir ? T_ - 3 : 2) * 512);
    x3 = *(const uint2*)(xgbase + (long)(dir ? T_ - 4 : 3) * 512);
    x4 = *(const uint2*)(xgbase + (long)(dir ? T_ - 5 : 4) * 512);
    x5 = *(const uint2*)(xgbase + (long)(dir ? T_ - 6 : 5) * 512);
    x6 = *(const uint2*)(xgbase + (long)(dir ? T_ - 7 : 6) * 512);
    x7 = *(const uint2*)(xgbase + (long)(dir ? T_ - 8 : 7) * 512);
  }
  __syncthreads();

  for (int ph = 0; ph < 64; ++ph) {
    const int t0ph = ph * 8;
    LSTEP(0, x0);
    LSTEP(1, x1);
    LSTEP(2, x2);
    LSTEP(3, x3);
    LSTEP(4, x4);
    LSTEP(5, x5);
    LSTEP(6, x6);
    LSTEP(7, x7);
  }
}

// ---------------- Attention pool + LayerNorm + FC (fp16 hio) ---------------
__global__ __launch_bounds__(256) void head_kernel(
    const ushort* __restrict__ hio, const float* __restrict__ attn_w,
    const float* __restrict__ attn_b, const float* __restrict__ ln_g,
    const float* __restrict__ ln_b, const float* __restrict__ fc_w,
    const float* __restrict__ fc_b, float* __restrict__ res) {
  const int b = blockIdx.x;
  const int tid = threadIdx.x;
  __shared__ __align__(16) float aw[128];
  __shared__ float l[T_];
  __shared__ float red[16];
  __shared__ float pp[2][128];
  __shared__ float normed[128];
  if (tid < 128) aw[tid] = attn_w[tid];
  __syncthreads();
  const float ab = attn_b[0];

  for (int t = tid; t < T_; t += 256) {
    const ushort* row = hio + ((long)b * T_ + t) * 128;
    float a = ab;
#pragma unroll
    for (int d = 0; d < 128; d += 8) {
      uint4 v = *(const uint4*)(row + d);
      float2 p0 = __half22float2(*(const __half2*)&v.x);
      float2 p1 = __half22float2(*(const __half2*)&v.y);
      float2 p2 = __half22float2(*(const __half2*)&v.z);
      float2 p3 = __half22float2(*(const __half2*)&v.w);
      a += p0.x * aw[d] + p0.y * aw[d + 1] + p1.x * aw[d + 2] +
           p1.y * aw[d + 3] + p2.x * aw[d + 4] + p2.y * aw[d + 5] +
           p3.x * aw[d + 6] + p3.y * aw[d + 7];
    }
    l[t] = a;
  }
  __syncthreads();

  float v0 = l[tid], v1 = l[tid + 256];
  float m = fmaxf(v0, v1);
#pragma unroll
  for (int off = 32; off >= 1; off >>= 1) m = fmaxf(m, __shfl_xor(m, off));
  if ((tid & 63) == 0) red[tid >> 6] = m;
  __syncthreads();
  m = fmaxf(fmaxf(red[0], red[1]), fmaxf(red[2], red[3]));
  float e0 = __expf(v0 - m), e1 = __expf(v1 - m);
  float ssum = e0 + e1;
#pragma unroll
  for (int off = 32; off >= 1; off >>= 1) ssum += __shfl_xor(ssum, off);
  if ((tid & 63) == 0) red[4 + (tid >> 6)] = ssum;
  __syncthreads();
  float inv = 1.f / (red[4] + red[5] + red[6] + red[7]);
  l[tid] = e0 * inv;
  l[tid + 256] = e1 * inv;
  __syncthreads();

  const int d = tid & 127, half = tid >> 7;
  float p = 0.f;
  for (int t = half * 256; t < half * 256 + 256; ++t)
    p += l[t] * h2f(hio[((long)b * T_ + t) * 128 + d]);
  pp[half][d] = p;
  __syncthreads();

  if (tid < 128) {
    float pv = pp[0][tid] + pp[1][tid];
    float s1 = pv, s2 = pv * pv;
#pragma unroll
    for (int off = 32; off >= 1; off >>= 1) {
      s1 += __shfl_xor(s1, off);
      s2 += __shfl_xor(s2, off);
    }
    if ((tid & 63) == 0) {
      red[8 + (tid >> 6) * 2] = s1;
      red[9 + (tid >> 6) * 2] = s2;
    }
  }
  __syncthreads();
  if (tid < 128) {
    float s1 = red[8] + red[10], s2 = red[9] + red[11];
    float mu = s1 * (1.f / 128.f);
    float var = s2 * (1.f / 128.f) - mu * mu;
    float rinv = rsqrtf(var + 1e-5f);
    float pv = pp[0][tid] + pp[1][tid];
    normed[tid] = (pv - mu) * rinv * ln_g[tid] + ln_b[tid];
  }
  __syncthreads();

  if (tid < 2) {
    float a = fc_b[tid];
    for (int d2 = 0; d2 < 128; ++d2) a += normed[d2] * fc_w[tid * 128 + d2];
    res[b * 2 + tid] = a;
  }
}

extern "C" void kernel_launch(void* const* d_in, const int* in_sizes, int n_in,
                              void* d_out, int out_size, void* d_ws,
                              size_t ws_size, hipStream_t stream) {
  const float* x = (const float*)d_in[0];
  const float* conv_w = (const float*)d_in[1];
  const float* conv_b = (const float*)d_in[2];
  const float* w_ih_f = (const float*)d_in[3];
  const float* w_hh_f = (const float*)d_in[4];
  const float* b_f = (const float*)d_in[5];
  const float* w_ih_b = (const float*)d_in[6];
  const float* w_hh_b = (const float*)d_in[7];
  const float* b_b = (const float*)d_in[8];
  const float* attn_w = (const float*)d_in[9];
  const float* attn_b = (const float*)d_in[10];
  const float* ln_g = (const float*)d_in[11];
  const float* ln_b = (const float*)d_in[12];
  const float* fc_w = (const float*)d_in[13];
  const float* fc_b = (const float*)d_in[14];
  float* res = (float*)d_out;

  // ws layout (~169 MiB):
  char* ws = (char*)d_ws;
  ushort* wbT = (ushort*)ws;                       // 294,912 B
  ushort* wP = (ushort*)(ws + 0x60000);            // 131,072 B (bf16, scaled)
  ushort* whhP = (ushort*)(ws + 0x80000);          // 65,536 B (fp16, scaled)
  float* biasP = (float*)(ws + 0x90000);           // 2,048 B (scaled)
  ushort* xgP = (ushort*)(ws + 0x100000);          // 134,217,728 B (fp16)
  ushort* hout = (ushort*)(ws + 0x100000 + 134217728);  // 33,554,432 B (fp16)

  pack_w_kernel<<<576, 256, 0, stream>>>(conv_w, wbT);
  pack_wiP_kernel<<<256, 256, 0, stream>>>(w_ih_f, w_ih_b, wP);
  pack_whhP_kernel<<<128, 256, 0, stream>>>(w_hh_f, w_hh_b, whhP);
  pack_biasP_kernel<<<2, 256, 0, stream>>>(b_f, b_b, biasP);
  conv_xg_kernel<<<B_ * (T_ / 128), 256, 0, stream>>>(x, wbT, conv_b, wP,
                                                      biasP, xgP);
  lstm_seq_kernel<<<128, 256, 0, stream>>>(whhP, xgP, hout);
  head_kernel<<<B_, 256, 0, stream>>>(hout, attn_w, attn_b, ln_g, ln_b, fc_w,
                                      fc_b, res);
}